// Round 9
// baseline (76.215 us; speedup 1.0000x reference)
//
#include <hip/hip_runtime.h>
#include <cmath>

typedef float f32x4 __attribute__((ext_vector_type(4)));

#define TT 8192
#define NV 65

__device__ __forceinline__ float dot4acc(f32x4 a, f32x4 b, float acc) {
  acc = fmaf(a[0], b[0], acc);
  acc = fmaf(a[1], b[1], acc);
  acc = fmaf(a[2], b[2], acc);
  acc = fmaf(a[3], b[3], acc);
  return acc;
}

// Kernel A: cpt[b*6+e][t] = softmax(embed_w[x])[b,t,e]
__global__ __launch_bounds__(128) void cp_kernel(const int* __restrict__ x,
                                                 const float* __restrict__ ew,
                                                 float* __restrict__ cpt) {
  int n = blockIdx.x * 128 + threadIdx.x;  // n = b*8192 + t, 256 blocks
  int b = n >> 13, t = n & 8191;
  int xv = x[n];
  float v[6];
#pragma unroll
  for (int e = 0; e < 6; ++e) v[e] = ew[xv * 6 + e];
  float m = v[0];
#pragma unroll
  for (int e = 1; e < 6; ++e) m = fmaxf(m, v[e]);
  float s = 0.f;
#pragma unroll
  for (int e = 0; e < 6; ++e) { v[e] = expf(v[e] - m); s += v[e]; }
  float inv = 1.f / s;
#pragma unroll
  for (int e = 0; e < 6; ++e) cpt[(b * 6 + e) * TT + t] = v[e] * inv;
}

// Fused main kernel — R8 structure + software pipeline:
//  * double-buffered LDS stage (one barrier per chunk, not two)
//  * async-stage split: issue next chunk's cp loads BEFORE compute,
//    ds_write them AFTER compute (T14; global latency hides under FMAs)
//  * W register-prefetched one chunk ahead (issued before cp loads so the
//    ds_write's vmcnt wait also covers W -> next compute starts stall-free)
// Row pairing (R8): block j, wave w owns low {8j+2w,+1} (predicated off
// past diagonal) and high {8184-8j+2w,+1} (active the whole sweep).
__global__ __launch_bounds__(256, 2) void sticky_fused(
    const float* __restrict__ W, const float* __restrict__ cpt,
    const float* __restrict__ rtp, const float* __restrict__ tp,
    const float* __restrict__ CT, const float* __restrict__ RT,
    const float* __restrict__ OM, float* __restrict__ out) {
  __shared__ __align__(16) float cp_lds[2][24][256];
  __shared__ float ws_lds[4][4][24];
  const int j = blockIdx.x;
  const int tid = threadIdx.x;
  const int w = tid >> 6, lane = tid & 63;
  const int kl = lane * 4;
  const int l0 = 8 * j + 2 * w;         // low rows: l0, l0+1
  const int h0 = 8184 - 8 * j + 2 * w;  // high rows: h0, h0+1
  const int klow_end = l0 + 2;
  const int k_need = 8192 - 8 * j;
  const int nch = (k_need + 255) >> 8;  // >= 17, so pipeline always runs

  const float* wl = W + (size_t)l0 * TT;
  const float* wh = W + (size_t)h0 * TT;

  float acc[4][24];
#pragma unroll
  for (int r = 0; r < 4; ++r)
#pragma unroll
    for (int e = 0; e < 24; ++e) acc[r][e] = 0.f;

  // ---- prologue: W(chunk0) + stage chunk 0 into buf 0 ----
  f32x4 whc0 = __builtin_nontemporal_load(reinterpret_cast<const f32x4*>(wh + kl));
  f32x4 whc1 = __builtin_nontemporal_load(reinterpret_cast<const f32x4*>(wh + TT + kl));
  f32x4 wlc0 = __builtin_nontemporal_load(reinterpret_cast<const f32x4*>(wl + kl));
  f32x4 wlc1 = __builtin_nontemporal_load(reinterpret_cast<const f32x4*>(wl + TT + kl));
  {
    f32x4 s0[6];
#pragma unroll
    for (int i = 0; i < 6; ++i) {
      int f = tid + 256 * i;
      int e = f >> 6, c4 = (f & 63) * 4;
      s0[i] = *reinterpret_cast<const f32x4*>(&cpt[e * TT + c4]);
    }
#pragma unroll
    for (int i = 0; i < 6; ++i) {
      int f = tid + 256 * i;
      int e = f >> 6, c4 = (f & 63) * 4;
      *reinterpret_cast<f32x4*>(&cp_lds[0][e][c4]) = s0[i];
    }
  }
  __syncthreads();

  // ---- main pipelined loop: one barrier per chunk ----
#pragma unroll 1
  for (int ch = 0; ch < nch; ++ch) {
    const int cur = ch & 1;
    const int kc = ch << 8;
    const bool hn = (ch + 1 < nch);
    const int kn = hn ? kc + 256 : kc;       // harmless re-read on last chunk
    const bool lowc = kc < klow_end;         // wave-uniform
    const bool lown = kn < klow_end;

    // issue next-chunk W loads first (covered by the cp vmcnt wait below)
    f32x4 whn0 = __builtin_nontemporal_load(
        reinterpret_cast<const f32x4*>(wh + kn + kl));
    f32x4 whn1 = __builtin_nontemporal_load(
        reinterpret_cast<const f32x4*>(wh + TT + kn + kl));
    f32x4 wln0 = whn0, wln1 = whn1;
    if (lown) {
      wln0 = __builtin_nontemporal_load(
          reinterpret_cast<const f32x4*>(wl + kn + kl));
      wln1 = __builtin_nontemporal_load(
          reinterpret_cast<const f32x4*>(wl + TT + kn + kl));
    }
    // issue next-chunk cp loads (write-late after compute)
    f32x4 sreg[6];
    if (hn) {
#pragma unroll
      for (int i = 0; i < 6; ++i) {
        int f = tid + 256 * i;
        int e = f >> 6, c4 = (f & 63) * 4;
        sreg[i] = *reinterpret_cast<const f32x4*>(&cpt[e * TT + kn + c4]);
      }
    }

    // compute current chunk (hides the latency of the loads above).
    // Upper-tri of position_mask is exactly 0 (tril in setup), so the <=7
    // element over-read past a high row's diagonal adds exactly 0.
    if (lowc) {
#pragma unroll
      for (int e = 0; e < 24; ++e) {
        f32x4 c = *reinterpret_cast<const f32x4*>(&cp_lds[cur][e][kl]);
        acc[0][e] = dot4acc(wlc0, c, acc[0][e]);
        acc[1][e] = dot4acc(wlc1, c, acc[1][e]);
        acc[2][e] = dot4acc(whc0, c, acc[2][e]);
        acc[3][e] = dot4acc(whc1, c, acc[3][e]);
      }
    } else {
#pragma unroll
      for (int e = 0; e < 24; ++e) {
        f32x4 c = *reinterpret_cast<const f32x4*>(&cp_lds[cur][e][kl]);
        acc[2][e] = dot4acc(whc0, c, acc[2][e]);
        acc[3][e] = dot4acc(whc1, c, acc[3][e]);
      }
    }

    // write-late: stage next chunk into the other buffer
    if (hn) {
#pragma unroll
      for (int i = 0; i < 6; ++i) {
        int f = tid + 256 * i;
        int e = f >> 6, c4 = (f & 63) * 4;
        *reinterpret_cast<f32x4*>(&cp_lds[cur ^ 1][e][c4]) = sreg[i];
      }
    }
    whc0 = whn0;
    whc1 = whn1;
    wlc0 = wln0;
    wlc1 = wln1;
    __syncthreads();
  }

  // full 64-lane butterfly over the k split
#pragma unroll
  for (int r = 0; r < 4; ++r)
#pragma unroll
    for (int e = 0; e < 24; ++e) {
      float v = acc[r][e];
      v += __shfl_xor(v, 1);
      v += __shfl_xor(v, 2);
      v += __shfl_xor(v, 4);
      v += __shfl_xor(v, 8);
      v += __shfl_xor(v, 16);
      v += __shfl_xor(v, 32);
      acc[r][e] = v;
    }
  if (lane == 0) {
#pragma unroll
    for (int r = 0; r < 4; ++r)
#pragma unroll
      for (int e = 0; e < 24; ++e) ws_lds[w][r][e] = acc[r][e];
  }
  __syncthreads();

  // fused epilogue (R8-verbatim): lane -> (r,b) + v-chunk over wave's rows
  const int rb = lane & 15;
  const int r = rb >> 2, b = rb & 3, vi = lane >> 4;
  const int t = (r < 2) ? (l0 + r) : (h0 + (r - 2));
  float cp6[6], ws6[6];
#pragma unroll
  for (int e = 0; e < 6; ++e) {
    cp6[e] = cpt[(b * 6 + e) * TT + t];
    ws6[e] = ws_lds[w][r][b * 6 + e];
  }
  float score = 0.f;
#pragma unroll
  for (int e = 0; e < 6; ++e) score = fmaf(cp6[e], ws6[e], score);
  float rt = rtp[0];
  float temp = tp[0];
  float z = (score - rt * rt) / (temp * temp);
  float reset = 1.f / (1.f + expf(-z));  // saturates correctly at extremes
  float nc[6];
#pragma unroll
  for (int c = 0; c < 6; ++c) {
    float tc = 0.f, rc = 0.f;
#pragma unroll
    for (int e = 0; e < 6; ++e) {
      tc = fmaf(cp6[e], CT[e * 6 + c], tc);
      rc = fmaf(cp6[e], RT[e * 6 + c], rc);
    }
    nc[c] = reset * rc + (1.f - reset) * tc;
  }
  size_t obase = ((size_t)b * TT + t) * NV;
  for (int v = vi; v < NV; v += 4) {
    float o = 0.f;
#pragma unroll
    for (int c = 0; c < 6; ++c) o = fmaf(nc[c], OM[c * NV + v], o);
    out[obase + v] = o;
  }
}

extern "C" void kernel_launch(void* const* d_in, const int* in_sizes, int n_in,
                              void* d_out, int out_size, void* d_ws, size_t ws_size,
                              hipStream_t stream) {
  const int* x = (const int*)d_in[0];
  const float* ew = (const float*)d_in[1];
  const float* W = (const float*)d_in[2];
  const float* rtp = (const float*)d_in[3];
  const float* tp = (const float*)d_in[4];
  const float* CT = (const float*)d_in[5];
  const float* RT = (const float*)d_in[6];
  const float* OM = (const float*)d_in[7];
  float* out = (float*)d_out;
  float* cpt = (float*)d_ws;  // 24*8192 f32 = 786 KB

  hipLaunchKernelGGL(cp_kernel, dim3(256), dim3(128), 0, stream, x, ew, cpt);
  hipLaunchKernelGGL(sticky_fused, dim3(512), dim3(256), 0, stream,
                     W, cpt, rtp, tp, CT, RT, OM, out);
}